// Round 1
// baseline (220.572 us; speedup 1.0000x reference)
//
#include <hip/hip_runtime.h>
#include <hip/hip_bf16.h>

// SparseLinear forward as bf16 MFMA GEMM:  C[M,N] = A[M,K] * B[N,K]^T + bias
// M = T*B = 4096, N = C_OUT = 4096, K = C_IN = 4096.
// Step 1: convert fp32 x / weight -> bf16 in d_ws (RNE).
// Step 2: m97-structure GEMM: 128x128 tile, BK=32, 4 waves (2x2), 4x4 frags,
//         global_load_lds width=16 staging, fused bias epilogue.

typedef __bf16 bf16x8 __attribute__((ext_vector_type(8)));
typedef float f32x4 __attribute__((ext_vector_type(4)));
typedef unsigned short u16x8 __attribute__((ext_vector_type(8)));

constexpr int M = 4096;   // T*B
constexpr int N = 4096;   // C_OUT
constexpr int K = 4096;   // C_IN
constexpr int BM = 128, BN = 128, BK = 32;

__device__ __forceinline__ unsigned short f2bf_rne(float f) {
    unsigned int u = __float_as_uint(f);
    u += 0x7fffu + ((u >> 16) & 1u);   // round-to-nearest-even
    return (unsigned short)(u >> 16);
}

__global__ __launch_bounds__(256) void cvt_f32_bf16(const float* __restrict__ in,
                                                    unsigned short* __restrict__ out,
                                                    int n8) {
    int idx = blockIdx.x * blockDim.x + threadIdx.x;
    int stride = gridDim.x * blockDim.x;
    for (int i = idx; i < n8; i += stride) {
        long base = (long)i * 8;
        float4 v0 = *(const float4*)(in + base);
        float4 v1 = *(const float4*)(in + base + 4);
        u16x8 r;
        r[0] = f2bf_rne(v0.x); r[1] = f2bf_rne(v0.y);
        r[2] = f2bf_rne(v0.z); r[3] = f2bf_rne(v0.w);
        r[4] = f2bf_rne(v1.x); r[5] = f2bf_rne(v1.y);
        r[6] = f2bf_rne(v1.z); r[7] = f2bf_rne(v1.w);
        *(u16x8*)(out + base) = r;
    }
}

__global__ __launch_bounds__(256) void gemm_bt_bias(
    const unsigned short* __restrict__ A,   // [M][K] bf16 bits
    const unsigned short* __restrict__ B,   // [N][K] bf16 bits (weight)
    const float* __restrict__ bias,         // [N]
    float* __restrict__ C)                  // [M][N] fp32
{
    __shared__ unsigned short As[BM * BK];  // 8 KiB, linear row-major [128][32]
    __shared__ unsigned short Bs[BN * BK];  // 8 KiB

    // XCD-aware bijective swizzle (1024 wgs, 1024 % 8 == 0 -> simple form ok)
    const int wg  = blockIdx.x;
    const int swz = ((wg & 7) << 7) | (wg >> 3);
    const int bm  = swz >> 5;   // 32 tiles along M
    const int bn  = swz & 31;   // 32 tiles along N

    const int tid  = threadIdx.x;
    const int wave = tid >> 6;
    const int lane = tid & 63;
    const int wr = wave >> 1, wc = wave & 1;   // 2x2 wave grid, 64x64 per wave

    const int brow = bm * BM;
    const int bcol = bn * BN;

    // Staging: element e = issue*2048 + wave*512 + lane*8 of the [128][32] tile.
    const int e0 = wave * 512 + lane * 8;
    const int r0 = e0 >> 5;           // rows 0..63   (issue 0)
    const int c0 = e0 & 31;
    const int r1 = r0 + 64;           // rows 64..127 (issue 1)

    const unsigned short* Ag0 = A + (long)(brow + r0) * K + c0;
    const unsigned short* Ag1 = A + (long)(brow + r1) * K + c0;
    const unsigned short* Bg0 = B + (long)(bcol + r0) * K + c0;
    const unsigned short* Bg1 = B + (long)(bcol + r1) * K + c0;

    // wave-uniform LDS bases: HW writes lane l at base + l*16B (linear layout!)
    unsigned short* AsW0 = As + wave * 512;
    unsigned short* AsW1 = As + 2048 + wave * 512;
    unsigned short* BsW0 = Bs + wave * 512;
    unsigned short* BsW1 = Bs + 2048 + wave * 512;

    f32x4 acc[4][4];
#pragma unroll
    for (int m = 0; m < 4; ++m)
#pragma unroll
        for (int n = 0; n < 4; ++n)
            acc[m][n] = (f32x4){0.f, 0.f, 0.f, 0.f};

    // MFMA 16x16x32 fragment addressing: lane holds row=(lane&15),
    // k = (lane>>4)*8 + j  (8 contiguous bf16 = one ds_read_b128)
    const int arow  = wr * 64 + (lane & 15);
    const int brow_f = wc * 64 + (lane & 15);
    const int koff  = (lane >> 4) * 8;

    for (int kt = 0; kt < K; kt += BK) {
        __builtin_amdgcn_global_load_lds(
            (const __attribute__((address_space(1))) void*)(Ag0 + kt),
            (__attribute__((address_space(3))) void*)AsW0, 16, 0, 0);
        __builtin_amdgcn_global_load_lds(
            (const __attribute__((address_space(1))) void*)(Ag1 + kt),
            (__attribute__((address_space(3))) void*)AsW1, 16, 0, 0);
        __builtin_amdgcn_global_load_lds(
            (const __attribute__((address_space(1))) void*)(Bg0 + kt),
            (__attribute__((address_space(3))) void*)BsW0, 16, 0, 0);
        __builtin_amdgcn_global_load_lds(
            (const __attribute__((address_space(1))) void*)(Bg1 + kt),
            (__attribute__((address_space(3))) void*)BsW1, 16, 0, 0);
        __syncthreads();   // compiler drains vmcnt before s_barrier

        bf16x8 a[4], b[4];
#pragma unroll
        for (int m = 0; m < 4; ++m)
            a[m] = *(const bf16x8*)(As + (arow + m * 16) * BK + koff);
#pragma unroll
        for (int n = 0; n < 4; ++n)
            b[n] = *(const bf16x8*)(Bs + (brow_f + n * 16) * BK + koff);

#pragma unroll
        for (int m = 0; m < 4; ++m)
#pragma unroll
            for (int n = 0; n < 4; ++n)
                acc[m][n] = __builtin_amdgcn_mfma_f32_16x16x32_bf16(
                    a[m], b[n], acc[m][n], 0, 0, 0);
        __syncthreads();   // protect LDS before next stage
    }

    // Epilogue: C/D layout (verified m89): col = lane&15, row = (lane>>4)*4 + j
#pragma unroll
    for (int n = 0; n < 4; ++n) {
        const int col = bcol + wc * 64 + n * 16 + (lane & 15);
        const float bs = bias[col];
#pragma unroll
        for (int m = 0; m < 4; ++m) {
            const int row0 = brow + wr * 64 + m * 16 + (lane >> 4) * 4;
#pragma unroll
            for (int j = 0; j < 4; ++j) {
                C[(long)(row0 + j) * N + col] = acc[m][n][j] + bs;
            }
        }
    }
}

extern "C" void kernel_launch(void* const* d_in, const int* in_sizes, int n_in,
                              void* d_out, int out_size, void* d_ws, size_t ws_size,
                              hipStream_t stream) {
    const float* x    = (const float*)d_in[0];   // [T,B,C_IN] = [M,K]
    const float* w    = (const float*)d_in[1];   // [C_OUT,C_IN] = [N,K]
    const float* bias = (const float*)d_in[2];   // [N]
    float* out = (float*)d_out;                  // [M,N]

    unsigned short* Abf = (unsigned short*)d_ws;           // 32 MiB
    unsigned short* Bbf = Abf + (size_t)M * K;             // 32 MiB

    const int n8 = (M * K) / 8;   // 2,097,152 vec8 chunks each
    cvt_f32_bf16<<<2048, 256, 0, stream>>>(x, Abf, n8);
    cvt_f32_bf16<<<2048, 256, 0, stream>>>(w, Bbf, n8);

    dim3 grid((M / BM) * (N / BN));   // 1024 blocks
    gemm_bt_bias<<<grid, 256, 0, stream>>>(Abf, Bbf, bias, out);
}

// Round 2
// 155.705 us; speedup vs baseline: 1.4166x; 1.4166x over previous
//
#include <hip/hip_runtime.h>
#include <hip/hip_bf16.h>

// SparseLinear forward as bf16 MFMA GEMM:  C[M,N] = A[M,K] * B[N,K]^T + bias
// 8-phase-style pipelined GEMM: 256x256 tile, BK=32, 8 waves (2Mx4N),
// 3-deep LDS ring (96 KiB), counted vmcnt(4), XOR-swizzled LDS, setprio MFMA.

typedef __bf16 bf16x8 __attribute__((ext_vector_type(8)));
typedef float f32x4 __attribute__((ext_vector_type(4)));
typedef unsigned short u16x8 __attribute__((ext_vector_type(8)));

constexpr int M = 4096;   // T*B
constexpr int N = 4096;   // C_OUT
constexpr int K = 4096;   // C_IN
constexpr int BM = 256, BN = 256, BK = 32;
constexpr int NT = K / BK;              // 128 K-tiles
constexpr int BUF_ELEMS = BM * BK;      // 8192 elems per operand per buffer
constexpr int TILE_ELEMS = 2 * BUF_ELEMS; // A+B per buffer = 16384

__device__ __forceinline__ unsigned short f2bf_rne(float f) {
    unsigned int u = __float_as_uint(f);
    u += 0x7fffu + ((u >> 16) & 1u);   // round-to-nearest-even
    return (unsigned short)(u >> 16);
}

__global__ __launch_bounds__(256) void cvt_f32_bf16(const float* __restrict__ in,
                                                    unsigned short* __restrict__ out,
                                                    int n8) {
    int idx = blockIdx.x * blockDim.x + threadIdx.x;
    int stride = gridDim.x * blockDim.x;
    for (int i = idx; i < n8; i += stride) {
        long base = (long)i * 8;
        float4 v0 = *(const float4*)(in + base);
        float4 v1 = *(const float4*)(in + base + 4);
        u16x8 r;
        r[0] = f2bf_rne(v0.x); r[1] = f2bf_rne(v0.y);
        r[2] = f2bf_rne(v0.z); r[3] = f2bf_rne(v0.w);
        r[4] = f2bf_rne(v1.x); r[5] = f2bf_rne(v1.y);
        r[6] = f2bf_rne(v1.z); r[7] = f2bf_rne(v1.w);
        *(u16x8*)(out + base) = r;
    }
}

// Stage one 128-row x 32-col half of one operand tile into LDS (linear dest,
// pre-swizzled global source: colgrp_src = colgrp ^ ((row>>1)&3)).
// One call = 512 threads x 16 B = 8 KiB; LDS dest is wave-uniform + lane*16.
__device__ __forceinline__ void stage_half(const unsigned short* __restrict__ g,
                                           size_t grow0, int kt,
                                           unsigned short* ldsbase, int h,
                                           int tid, int wave) {
    const int rl = h * 128 + (tid >> 2);                 // tile row 0..255
    const int cg = (tid & 3) ^ ((rl >> 1) & 3);          // swizzled col group
    const unsigned short* src = g + (grow0 + (size_t)rl) * (size_t)K
                                  + (size_t)(kt + cg * 8);
    unsigned short* dst = ldsbase + h * 4096 + wave * 512;
    __builtin_amdgcn_global_load_lds(
        (const __attribute__((address_space(1))) void*)src,
        (__attribute__((address_space(3))) void*)dst, 16, 0, 0);
}

__global__ __launch_bounds__(512, 2) void gemm_bt_bias_8p(
    const unsigned short* __restrict__ A,   // [M][K] bf16 bits
    const unsigned short* __restrict__ B,   // [N][K] bf16 bits
    const float* __restrict__ bias,         // [N]
    float* __restrict__ C)                  // [M][N] fp32
{
    __shared__ unsigned short lds[3 * TILE_ELEMS];   // 96 KiB, 3-deep ring

    // XCD-aware bijective swizzle: 256 wgs, 256 % 8 == 0
    const int wg = blockIdx.x;
    const int s  = ((wg & 7) << 5) | (wg >> 3);
    const int bm = s >> 4, bn = s & 15;
    const size_t brow = (size_t)bm * BM;
    const size_t bcol = (size_t)bn * BN;

    const int tid  = threadIdx.x;
    const int wave = tid >> 6;
    const int lane = tid & 63;
    const int wr = wave >> 2;       // 0..1  (2 M-waves, 128 rows each)
    const int wc = wave & 3;        // 0..3  (4 N-waves, 64 cols each)
    const int lr = lane & 15;       // fragment row-in-16
    const int kg = lane >> 4;       // k-group 0..3

    // Phase-invariant swizzled fragment bases (swizzle term constant under
    // row += 16k since ((row+16k)>>1)&3 == (row>>1)&3).
    const int a_row0 = wr * 128 + lr;
    const int b_row0 = wc * 64 + lr;
    const int koffA = ((kg ^ ((a_row0 >> 1) & 3)) << 3);
    const int koffB = ((kg ^ ((b_row0 >> 1) & 3)) << 3);

    f32x4 acc[8][4];
#pragma unroll
    for (int m = 0; m < 8; ++m)
#pragma unroll
        for (int n = 0; n < 4; ++n)
            acc[m][n] = (f32x4){0.f, 0.f, 0.f, 0.f};

    // ---- prologue: stage tiles 0 (buf0) and 1 (buf1), 8 loads ----
    stage_half(A, brow, 0, lds, 0, tid, wave);
    stage_half(A, brow, 0, lds, 1, tid, wave);
    stage_half(B, bcol, 0, lds + BUF_ELEMS, 0, tid, wave);
    stage_half(B, bcol, 0, lds + BUF_ELEMS, 1, tid, wave);
    stage_half(A, brow, BK, lds + TILE_ELEMS, 0, tid, wave);
    stage_half(A, brow, BK, lds + TILE_ELEMS, 1, tid, wave);
    stage_half(B, bcol, BK, lds + TILE_ELEMS + BUF_ELEMS, 0, tid, wave);
    stage_half(B, bcol, BK, lds + TILE_ELEMS + BUF_ELEMS, 1, tid, wave);
    asm volatile("s_waitcnt vmcnt(4)" ::: "memory");   // tile 0 landed
    __builtin_amdgcn_s_barrier();

    int cb = 0;   // current ring slot
    for (int t = 0; t < NT; ++t) {
        unsigned short* bufA = lds + cb * TILE_ELEMS;
        unsigned short* bufB = bufA + BUF_ELEMS;
        const unsigned short* pA = bufA + a_row0 * 32 + koffA;
        const unsigned short* pB = bufB + b_row0 * 32 + koffB;
        const int pb = (cb >= 1) ? cb - 1 : 2;         // (cb+2)%3
        unsigned short* pbufA = lds + pb * TILE_ELEMS;
        unsigned short* pbufB = pbufA + BUF_ELEMS;
        const int ktp = (t + 2) * BK;
        const bool pf = (t + 2) < NT;

        bf16x8 af[4], bfr[4];

        // ================= phase 0 (m-half 0) =================
#pragma unroll
        for (int i = 0; i < 4; ++i)
            bfr[i] = *(const bf16x8*)(pB + i * 512);
#pragma unroll
        for (int i = 0; i < 4; ++i)
            af[i] = *(const bf16x8*)(pA + i * 512);
        if (pf) {   // prefetch A of tile t+2 (slot pb, free since end of t-1)
            stage_half(A, brow, ktp, pbufA, 0, tid, wave);
            stage_half(A, brow, ktp, pbufA, 1, tid, wave);
        }
        __builtin_amdgcn_s_barrier();
        asm volatile("s_waitcnt lgkmcnt(0)" ::: "memory");
        __builtin_amdgcn_sched_barrier(0);
        __builtin_amdgcn_s_setprio(1);
#pragma unroll
        for (int m = 0; m < 4; ++m)
#pragma unroll
            for (int n = 0; n < 4; ++n)
                acc[m][n] = __builtin_amdgcn_mfma_f32_16x16x32_bf16(
                    af[m], bfr[n], acc[m][n], 0, 0, 0);
        __builtin_amdgcn_s_setprio(0);
        __builtin_amdgcn_s_barrier();

        // ================= phase 1 (m-half 1) =================
#pragma unroll
        for (int i = 0; i < 4; ++i)
            af[i] = *(const bf16x8*)(pA + 2048 + i * 512);
        if (pf) {   // prefetch B of tile t+2
            stage_half(B, bcol, ktp, pbufB, 0, tid, wave);
            stage_half(B, bcol, ktp, pbufB, 1, tid, wave);
        }
        // Tile-boundary counted wait: drain tile t+1's 4 loads (oldest),
        // keep tile t+2's 4 in flight. Never vmcnt(0) in steady state.
        if (t + 2 < NT) {
            asm volatile("s_waitcnt vmcnt(4)" ::: "memory");
        } else if (t + 1 < NT) {
            asm volatile("s_waitcnt vmcnt(0)" ::: "memory");
        }
        __builtin_amdgcn_s_barrier();
        asm volatile("s_waitcnt lgkmcnt(0)" ::: "memory");
        __builtin_amdgcn_sched_barrier(0);
        __builtin_amdgcn_s_setprio(1);
#pragma unroll
        for (int m = 0; m < 4; ++m)
#pragma unroll
            for (int n = 0; n < 4; ++n)
                acc[4 + m][n] = __builtin_amdgcn_mfma_f32_16x16x32_bf16(
                    af[m], bfr[n], acc[4 + m][n], 0, 0, 0);
        __builtin_amdgcn_s_setprio(0);
        __builtin_amdgcn_s_barrier();

        cb = (cb >= 2) ? 0 : cb + 1;
    }

    // ---- epilogue: C/D layout col=lane&15, row=(lane>>4)*4+j; fused bias ----
#pragma unroll
    for (int n = 0; n < 4; ++n) {
        const size_t col = bcol + wc * 64 + n * 16 + lr;
        const float bs = bias[col];
#pragma unroll
        for (int m = 0; m < 8; ++m) {
            const size_t row0 = brow + (size_t)wr * 128 + m * 16 + kg * 4;
#pragma unroll
            for (int j = 0; j < 4; ++j) {
                C[(row0 + j) * N + col] = acc[m][n][j] + bs;
            }
        }
    }
}

extern "C" void kernel_launch(void* const* d_in, const int* in_sizes, int n_in,
                              void* d_out, int out_size, void* d_ws, size_t ws_size,
                              hipStream_t stream) {
    const float* x    = (const float*)d_in[0];   // [T,B,C_IN] = [M,K]
    const float* w    = (const float*)d_in[1];   // [C_OUT,C_IN] = [N,K]
    const float* bias = (const float*)d_in[2];   // [N]
    float* out = (float*)d_out;                  // [M,N]

    unsigned short* Abf = (unsigned short*)d_ws;           // 32 MiB
    unsigned short* Bbf = Abf + (size_t)M * K;             // 32 MiB

    const int n8 = (M * K) / 8;
    cvt_f32_bf16<<<2048, 256, 0, stream>>>(x, Abf, n8);
    cvt_f32_bf16<<<2048, 256, 0, stream>>>(w, Bbf, n8);

    dim3 grid((M / BM) * (N / BN));   // 256 blocks, 1 per CU
    gemm_bt_bias_8p<<<grid, 512, 0, stream>>>(Abf, Bbf, bias, out);
}

// Round 3
// 153.158 us; speedup vs baseline: 1.4402x; 1.0166x over previous
//
#include <hip/hip_runtime.h>
#include <hip/hip_bf16.h>

// SparseLinear forward as bf16 MFMA GEMM:  C[M,N] = A[M,K] * B[N,K]^T + bias
// Free-running pipelined GEMM: 256x256 tile, BK=64 split into k-half units,
// 2-deep LDS dbuf (128 KiB), only TWO counted vmcnt(4)+barrier points per
// K-tile (no per-phase lockstep), zero-conflict XOR swizzle, fused bias.

typedef __bf16 bf16x8 __attribute__((ext_vector_type(8)));
typedef float f32x4 __attribute__((ext_vector_type(4)));
typedef unsigned short u16x8 __attribute__((ext_vector_type(8)));

constexpr int M = 4096;   // T*B
constexpr int N = 4096;   // C_OUT
constexpr int K = 4096;   // C_IN
constexpr int BM = 256, BN = 256, BK = 64;
constexpr int NT = K / BK;          // 64 K-tiles
// One dbuf = 32768 elems (64 KiB): [A_k0 8192][A_k1 8192][B_k0 8192][B_k1 8192]
constexpr int DBUF = 32768;
constexpr int A_K0 = 0, A_K1 = 8192, B_K0 = 16384, B_K1 = 24576;

__device__ __forceinline__ unsigned short f2bf_rne(float f) {
    unsigned int u = __float_as_uint(f);
    u += 0x7fffu + ((u >> 16) & 1u);   // round-to-nearest-even
    return (unsigned short)(u >> 16);
}

__global__ __launch_bounds__(256) void cvt_f32_bf16(const float* __restrict__ in,
                                                    unsigned short* __restrict__ out,
                                                    int n8) {
    int idx = blockIdx.x * blockDim.x + threadIdx.x;
    int stride = gridDim.x * blockDim.x;
    for (int i = idx; i < n8; i += stride) {
        long base = (long)i * 8;
        float4 v0 = *(const float4*)(in + base);
        float4 v1 = *(const float4*)(in + base + 4);
        u16x8 r;
        r[0] = f2bf_rne(v0.x); r[1] = f2bf_rne(v0.y);
        r[2] = f2bf_rne(v0.z); r[3] = f2bf_rne(v0.w);
        r[4] = f2bf_rne(v1.x); r[5] = f2bf_rne(v1.y);
        r[6] = f2bf_rne(v1.z); r[7] = f2bf_rne(v1.w);
        *(u16x8*)(out + base) = r;
    }
}

// Stage one k-half unit ([256 rows][32 k] = 16 KiB, 2 global_load_lds) into
// LDS (linear dest, pre-swizzled global source: cg ^= (row>>1)&3).
__device__ __forceinline__ void stage_unit(const unsigned short* __restrict__ g,
                                           size_t grow0, int kcol0,
                                           unsigned short* unitbase,
                                           int tid, int wave) {
#pragma unroll
    for (int i = 0; i < 2; ++i) {
        const int row = i * 128 + (tid >> 2);
        const int cg  = (tid & 3) ^ ((row >> 1) & 3);
        const unsigned short* src = g + (grow0 + (size_t)row) * (size_t)K
                                      + (size_t)(kcol0 + cg * 8);
        unsigned short* dst = unitbase + i * 4096 + wave * 512;
        __builtin_amdgcn_global_load_lds(
            (const __attribute__((address_space(1))) void*)src,
            (__attribute__((address_space(3))) void*)dst, 16, 0, 0);
    }
}

__global__ __launch_bounds__(512, 2) void gemm_bt_bias_fr(
    const unsigned short* __restrict__ A,   // [M][K] bf16 bits
    const unsigned short* __restrict__ B,   // [N][K] bf16 bits
    const float* __restrict__ bias,         // [N]
    float* __restrict__ C)                  // [M][N] fp32
{
    __shared__ unsigned short lds[2 * DBUF];   // 128 KiB

    // XCD-aware bijective swizzle: 256 wgs, 256 % 8 == 0
    const int wg = blockIdx.x;
    const int s  = ((wg & 7) << 5) | (wg >> 3);
    const int bm = s >> 4, bn = s & 15;
    const size_t brow = (size_t)bm * BM;
    const size_t bcol = (size_t)bn * BN;

    const int tid  = threadIdx.x;
    const int wave = tid >> 6;
    const int lane = tid & 63;
    const int wr = wave >> 2;       // 0..1  (2 M-waves, 128 rows each)
    const int wc = wave & 3;        // 0..3  (4 N-waves, 64 cols each)
    const int lr = lane & 15;       // fragment row-in-16
    const int kg = lane >> 4;       // k-group 0..3

    const int a_row0 = wr * 128 + lr;
    const int b_row0 = wc * 64 + lr;
    const int koffA = ((kg ^ ((a_row0 >> 1) & 3)) << 3);
    const int koffB = ((kg ^ ((b_row0 >> 1) & 3)) << 3);
    const int aoff = a_row0 * 32 + koffA;   // elem offset within a k-half unit
    const int boff = b_row0 * 32 + koffB;

    f32x4 acc[8][4];
#pragma unroll
    for (int m = 0; m < 8; ++m)
#pragma unroll
        for (int n = 0; n < 4; ++n)
            acc[m][n] = (f32x4){0.f, 0.f, 0.f, 0.f};

    // ---- prologue: stage tile 0's 4 units (8 loads) ----
    stage_unit(A, brow, 0,  lds + A_K0, tid, wave);
    stage_unit(B, bcol, 0,  lds + B_K0, tid, wave);
    stage_unit(A, brow, 32, lds + A_K1, tid, wave);
    stage_unit(B, bcol, 32, lds + B_K1, tid, wave);
    asm volatile("s_waitcnt vmcnt(4)" ::: "memory");   // A_k0, B_k0 landed
    __builtin_amdgcn_s_barrier();
    __builtin_amdgcn_sched_barrier(0);

    for (int t = 0; t < NT; ++t) {
        unsigned short* db = lds + (t & 1) * DBUF;        // compute buffer
        unsigned short* pb = lds + ((t & 1) ^ 1) * DBUF;  // prefetch target
        const int ktn = (t + 1) * BK;
        const bool pf = (t + 1) < NT;

        // ================= half 0 (ks = 0) =================
        if (pf) {
            stage_unit(A, brow, ktn,      pb + A_K0, tid, wave);
            stage_unit(B, bcol, ktn,      pb + B_K0, tid, wave);
        }
        {
            const unsigned short* pA = db + A_K0 + aoff;
            const unsigned short* pB = db + B_K0 + boff;
            bf16x8 bfr[4], af[8];
#pragma unroll
            for (int n = 0; n < 4; ++n)
                bfr[n] = *(const bf16x8*)(pB + n * 512);
#pragma unroll
            for (int m = 0; m < 8; ++m)
                af[m] = *(const bf16x8*)(pA + m * 512);
#pragma unroll
            for (int m = 0; m < 8; ++m)
#pragma unroll
                for (int n = 0; n < 4; ++n)
                    acc[m][n] = __builtin_amdgcn_mfma_f32_16x16x32_bf16(
                        af[m], bfr[n], acc[m][n], 0, 0, 0);
        }
        __builtin_amdgcn_sched_barrier(0);
        // A_k1(t), B_k1(t) must land before half 1's reads.
        if (pf) {
            asm volatile("s_waitcnt vmcnt(4)" ::: "memory");
        } else {
            asm volatile("s_waitcnt vmcnt(0)" ::: "memory");
        }
        __builtin_amdgcn_s_barrier();
        __builtin_amdgcn_sched_barrier(0);

        // ================= half 1 (ks = 1) =================
        if (pf) {
            stage_unit(A, brow, ktn + 32, pb + A_K1, tid, wave);
            stage_unit(B, bcol, ktn + 32, pb + B_K1, tid, wave);
        }
        {
            const unsigned short* pA = db + A_K1 + aoff;
            const unsigned short* pB = db + B_K1 + boff;
            bf16x8 bfr[4], af[8];
#pragma unroll
            for (int n = 0; n < 4; ++n)
                bfr[n] = *(const bf16x8*)(pB + n * 512);
#pragma unroll
            for (int m = 0; m < 8; ++m)
                af[m] = *(const bf16x8*)(pA + m * 512);
#pragma unroll
            for (int m = 0; m < 8; ++m)
#pragma unroll
                for (int n = 0; n < 4; ++n)
                    acc[m][n] = __builtin_amdgcn_mfma_f32_16x16x32_bf16(
                        af[m], bfr[n], acc[m][n], 0, 0, 0);
        }
        __builtin_amdgcn_sched_barrier(0);
        // A_k0(t+1), B_k0(t+1) must land before next tile's half-0 reads.
        if (pf) {
            asm volatile("s_waitcnt vmcnt(4)" ::: "memory");
            __builtin_amdgcn_s_barrier();
            __builtin_amdgcn_sched_barrier(0);
        }
    }

    // ---- epilogue: C/D layout col=lane&15, row=(lane>>4)*4+j; fused bias ----
#pragma unroll
    for (int n = 0; n < 4; ++n) {
        const size_t col = bcol + wc * 64 + n * 16 + lr;
        const float bs = bias[col];
#pragma unroll
        for (int m = 0; m < 8; ++m) {
            const size_t row0 = brow + (size_t)wr * 128 + m * 16 + kg * 4;
#pragma unroll
            for (int j = 0; j < 4; ++j) {
                C[(row0 + j) * N + col] = acc[m][n][j] + bs;
            }
        }
    }
}

extern "C" void kernel_launch(void* const* d_in, const int* in_sizes, int n_in,
                              void* d_out, int out_size, void* d_ws, size_t ws_size,
                              hipStream_t stream) {
    const float* x    = (const float*)d_in[0];   // [T,B,C_IN] = [M,K]
    const float* w    = (const float*)d_in[1];   // [C_OUT,C_IN] = [N,K]
    const float* bias = (const float*)d_in[2];   // [N]
    float* out = (float*)d_out;                  // [M,N]

    unsigned short* Abf = (unsigned short*)d_ws;           // 32 MiB
    unsigned short* Bbf = Abf + (size_t)M * K;             // 32 MiB

    const int n8 = (M * K) / 8;
    cvt_f32_bf16<<<2048, 256, 0, stream>>>(x, Abf, n8);
    cvt_f32_bf16<<<2048, 256, 0, stream>>>(w, Bbf, n8);

    dim3 grid((M / BM) * (N / BN));   // 256 blocks, 1 per CU
    gemm_bt_bias_fr<<<grid, 512, 0, stream>>>(Abf, Bbf, bias, out);
}

// Round 4
// 152.940 us; speedup vs baseline: 1.4422x; 1.0014x over previous
//
#include <hip/hip_runtime.h>
#include <hip/hip_bf16.h>

// SparseLinear forward as bf16 MFMA GEMM:  C[M,N] = A[M,K] * B[N,K]^T + bias
// m201-style 8-phase schedule: 256x256 tile, BK=64, 8 waves (2Mx4N),
// 4 fine phases per K-tile (16 MFMA + 4/8 ds_read each, 2 barriers/phase),
// counted vmcnt(4) twice per tile, setprio around MFMA, XOR-swizzled LDS.

typedef __bf16 bf16x8 __attribute__((ext_vector_type(8)));
typedef float f32x4 __attribute__((ext_vector_type(4)));
typedef unsigned short u16x8 __attribute__((ext_vector_type(8)));

constexpr int M = 4096;   // T*B
constexpr int N = 4096;   // C_OUT
constexpr int K = 4096;   // C_IN
constexpr int BM = 256, BN = 256, BK = 64;
constexpr int NT = K / BK;          // 64 K-tiles
// One dbuf = 32768 elems (64 KiB): [A_k0][A_k1][B_k0][B_k1], each [256][32]
constexpr int DBUF = 32768;
constexpr int A_K0 = 0, A_K1 = 8192, B_K0 = 16384, B_K1 = 24576;

__device__ __forceinline__ unsigned short f2bf_rne(float f) {
    unsigned int u = __float_as_uint(f);
    u += 0x7fffu + ((u >> 16) & 1u);   // round-to-nearest-even
    return (unsigned short)(u >> 16);
}

__global__ __launch_bounds__(256) void cvt_f32_bf16(const float* __restrict__ in,
                                                    unsigned short* __restrict__ out,
                                                    int n8) {
    int idx = blockIdx.x * blockDim.x + threadIdx.x;
    int stride = gridDim.x * blockDim.x;
    for (int i = idx; i < n8; i += stride) {
        long base = (long)i * 8;
        float4 v0 = *(const float4*)(in + base);
        float4 v1 = *(const float4*)(in + base + 4);
        u16x8 r;
        r[0] = f2bf_rne(v0.x); r[1] = f2bf_rne(v0.y);
        r[2] = f2bf_rne(v0.z); r[3] = f2bf_rne(v0.w);
        r[4] = f2bf_rne(v1.x); r[5] = f2bf_rne(v1.y);
        r[6] = f2bf_rne(v1.z); r[7] = f2bf_rne(v1.w);
        *(u16x8*)(out + base) = r;
    }
}

// Stage one k-half unit ([256 rows][32 k] = 16 KiB, 2 global_load_lds) into
// LDS (linear dest, pre-swizzled global source: cg ^= (row>>1)&3).
__device__ __forceinline__ void stage_unit(const unsigned short* __restrict__ g,
                                           size_t grow0, int kcol0,
                                           unsigned short* unitbase,
                                           int tid, int wave) {
#pragma unroll
    for (int i = 0; i < 2; ++i) {
        const int row = i * 128 + (tid >> 2);
        const int cg  = (tid & 3) ^ ((row >> 1) & 3);
        const unsigned short* src = g + (grow0 + (size_t)row) * (size_t)K
                                      + (size_t)(kcol0 + cg * 8);
        unsigned short* dst = unitbase + i * 4096 + wave * 512;
        __builtin_amdgcn_global_load_lds(
            (const __attribute__((address_space(1))) void*)src,
            (__attribute__((address_space(3))) void*)dst, 16, 0, 0);
    }
}

__global__ __launch_bounds__(512, 2) void gemm_bt_bias_8p(
    const unsigned short* __restrict__ A,   // [M][K] bf16 bits
    const unsigned short* __restrict__ B,   // [N][K] bf16 bits
    const float* __restrict__ bias,         // [N]
    float* __restrict__ C)                  // [M][N] fp32
{
    __shared__ unsigned short lds[2 * DBUF];   // 128 KiB

    // XCD-aware bijective swizzle: 256 wgs, 256 % 8 == 0
    const int wg = blockIdx.x;
    const int s  = ((wg & 7) << 5) | (wg >> 3);
    const int bm = s >> 4, bn = s & 15;
    const size_t brow = (size_t)bm * BM;
    const size_t bcol = (size_t)bn * BN;

    const int tid  = threadIdx.x;
    const int wave = tid >> 6;
    const int lane = tid & 63;
    const int wr = wave >> 2;       // 0..1  (2 M-waves, 128 rows each)
    const int wc = wave & 3;        // 0..3  (4 N-waves, 64 cols each)
    const int lr = lane & 15;       // fragment row-in-16
    const int kg = lane >> 4;       // k-group 0..3

    const int a_row0 = wr * 128 + lr;
    const int b_row0 = wc * 64 + lr;
    const int koffA = ((kg ^ ((a_row0 >> 1) & 3)) << 3);
    const int koffB = ((kg ^ ((b_row0 >> 1) & 3)) << 3);
    const int aoff = a_row0 * 32 + koffA;   // elem offset within a k-half unit
    const int boff = b_row0 * 32 + koffB;

    f32x4 acc[8][4];
#pragma unroll
    for (int m = 0; m < 8; ++m)
#pragma unroll
        for (int n = 0; n < 4; ++n)
            acc[m][n] = (f32x4){0.f, 0.f, 0.f, 0.f};

    // ---- prologue: stage tile 0's 4 units (8 loads) ----
    stage_unit(A, brow, 0,  lds + A_K0, tid, wave);
    stage_unit(B, bcol, 0,  lds + B_K0, tid, wave);
    stage_unit(A, brow, 32, lds + A_K1, tid, wave);
    stage_unit(B, bcol, 32, lds + B_K1, tid, wave);
    asm volatile("s_waitcnt vmcnt(4)" ::: "memory");   // A_k0, B_k0 landed
    __builtin_amdgcn_s_barrier();

    for (int t = 0; t < NT; ++t) {
        unsigned short* db = lds + (t & 1) * DBUF;        // compute buffer
        unsigned short* pb = lds + ((t & 1) ^ 1) * DBUF;  // prefetch target
        const int ktn = (t + 1) * BK;
        const bool pf = (t + 1) < NT;

        const unsigned short* pA0 = db + A_K0 + aoff;
        const unsigned short* pA1 = db + A_K1 + aoff;
        const unsigned short* pB0 = db + B_K0 + boff;
        const unsigned short* pB1 = db + B_K1 + boff;

        bf16x8 a[4], b[4];

        // ===== P1: quadrant (m-half 0, ks 0); stage A_k0(t+1) =====
#pragma unroll
        for (int n = 0; n < 4; ++n) b[n] = *(const bf16x8*)(pB0 + n * 512);
#pragma unroll
        for (int m = 0; m < 4; ++m) a[m] = *(const bf16x8*)(pA0 + m * 512);
        if (pf) stage_unit(A, brow, ktn, pb + A_K0, tid, wave);
        __builtin_amdgcn_s_barrier();
        asm volatile("s_waitcnt lgkmcnt(0)" ::: "memory");
        __builtin_amdgcn_sched_barrier(0);
        __builtin_amdgcn_s_setprio(1);
#pragma unroll
        for (int m = 0; m < 4; ++m)
#pragma unroll
            for (int n = 0; n < 4; ++n)
                acc[m][n] = __builtin_amdgcn_mfma_f32_16x16x32_bf16(
                    a[m], b[n], acc[m][n], 0, 0, 0);
        __builtin_amdgcn_s_setprio(0);
        __builtin_amdgcn_s_barrier();

        // ===== P2: quadrant (m-half 1, ks 0), B-frags reused; stage B_k0(t+1)
#pragma unroll
        for (int m = 0; m < 4; ++m) a[m] = *(const bf16x8*)(pA0 + 2048 + m * 512);
        if (pf) stage_unit(B, bcol, ktn, pb + B_K0, tid, wave);
        __builtin_amdgcn_s_barrier();
        asm volatile("s_waitcnt lgkmcnt(0)" ::: "memory");
        __builtin_amdgcn_sched_barrier(0);
        __builtin_amdgcn_s_setprio(1);
#pragma unroll
        for (int m = 0; m < 4; ++m)
#pragma unroll
            for (int n = 0; n < 4; ++n)
                acc[4 + m][n] = __builtin_amdgcn_mfma_f32_16x16x32_bf16(
                    a[m], b[n], acc[4 + m][n], 0, 0, 0);
        __builtin_amdgcn_s_setprio(0);
        // W_b: A_k1(t), B_k1(t) (oldest 4 loads) must land before P3 reads.
        if (pf) { asm volatile("s_waitcnt vmcnt(4)" ::: "memory"); }
        else    { asm volatile("s_waitcnt vmcnt(0)" ::: "memory"); }
        __builtin_amdgcn_s_barrier();

        // ===== P3: quadrant (m-half 0, ks 1); stage A_k1(t+1) =====
#pragma unroll
        for (int n = 0; n < 4; ++n) b[n] = *(const bf16x8*)(pB1 + n * 512);
#pragma unroll
        for (int m = 0; m < 4; ++m) a[m] = *(const bf16x8*)(pA1 + m * 512);
        if (pf) stage_unit(A, brow, ktn + 32, pb + A_K1, tid, wave);
        __builtin_amdgcn_s_barrier();
        asm volatile("s_waitcnt lgkmcnt(0)" ::: "memory");
        __builtin_amdgcn_sched_barrier(0);
        __builtin_amdgcn_s_setprio(1);
#pragma unroll
        for (int m = 0; m < 4; ++m)
#pragma unroll
            for (int n = 0; n < 4; ++n)
                acc[m][n] = __builtin_amdgcn_mfma_f32_16x16x32_bf16(
                    a[m], b[n], acc[m][n], 0, 0, 0);
        __builtin_amdgcn_s_setprio(0);
        __builtin_amdgcn_s_barrier();

        // ===== P4: quadrant (m-half 1, ks 1), B-frags reused; stage B_k1(t+1)
#pragma unroll
        for (int m = 0; m < 4; ++m) a[m] = *(const bf16x8*)(pA1 + 2048 + m * 512);
        if (pf) stage_unit(B, bcol, ktn + 32, pb + B_K1, tid, wave);
        __builtin_amdgcn_s_barrier();
        asm volatile("s_waitcnt lgkmcnt(0)" ::: "memory");
        __builtin_amdgcn_sched_barrier(0);
        __builtin_amdgcn_s_setprio(1);
#pragma unroll
        for (int m = 0; m < 4; ++m)
#pragma unroll
            for (int n = 0; n < 4; ++n)
                acc[4 + m][n] = __builtin_amdgcn_mfma_f32_16x16x32_bf16(
                    a[m], b[n], acc[4 + m][n], 0, 0, 0);
        __builtin_amdgcn_s_setprio(0);
        // W_a: A_k0(t+1), B_k0(t+1) (oldest 4) must land before P1(t+1) reads.
        if (pf) {
            asm volatile("s_waitcnt vmcnt(4)" ::: "memory");
            __builtin_amdgcn_s_barrier();
        }
    }

    // ---- epilogue: C/D layout col=lane&15, row=(lane>>4)*4+j; fused bias ----
#pragma unroll
    for (int n = 0; n < 4; ++n) {
        const size_t col = bcol + wc * 64 + n * 16 + lr;
        const float bs = bias[col];
#pragma unroll
        for (int m = 0; m < 8; ++m) {
            const size_t row0 = brow + (size_t)wr * 128 + m * 16 + kg * 4;
#pragma unroll
            for (int j = 0; j < 4; ++j) {
                C[(row0 + j) * N + col] = acc[m][n][j] + bs;
            }
        }
    }
}

extern "C" void kernel_launch(void* const* d_in, const int* in_sizes, int n_in,
                              void* d_out, int out_size, void* d_ws, size_t ws_size,
                              hipStream_t stream) {
    const float* x    = (const float*)d_in[0];   // [T,B,C_IN] = [M,K]
    const float* w    = (const float*)d_in[1];   // [C_OUT,C_IN] = [N,K]
    const float* bias = (const float*)d_in[2];   // [N]
    float* out = (float*)d_out;                  // [M,N]

    unsigned short* Abf = (unsigned short*)d_ws;           // 32 MiB
    unsigned short* Bbf = Abf + (size_t)M * K;             // 32 MiB

    const int n8 = (M * K) / 8;
    cvt_f32_bf16<<<2048, 256, 0, stream>>>(x, Abf, n8);
    cvt_f32_bf16<<<2048, 256, 0, stream>>>(w, Bbf, n8);

    dim3 grid((M / BM) * (N / BN));   // 256 blocks, 1 per CU
    gemm_bt_bias_8p<<<grid, 512, 0, stream>>>(Abf, Bbf, bias, out);
}